// Round 2
// baseline (158.569 us; speedup 1.0000x reference)
//
#include <hip/hip_runtime.h>
#include <math.h>

// Net_90434831385322: z = A + span*sigmoid(relu((x-A)/span @ W1 + b1) @ W2 + b2)
// BATCH=4194304, OBS=4, HID=64, ACT=4, all fp32.
//
// R5: SGPR weights + tied-accumulator v_pk_fma_f32. Post-mortem of R4:
//   (1) untied "=v" asm outputs added ~2 marshaling v_movs per fma
//       (counters: 7900 VALU instrs/thread back-solved from VALUBusy, vs
//       2900 intended) -> fix: tie acc with "+v", d==src2, in-place.
//   (2) LDS broadcast weight reads are a per-CU pipe bottleneck: 8 blk/CU
//       x 4 waves x 64 j x ~12cyc/ds_read_b128 ~= 46us of redundant
//       broadcast traffic (32 waves re-read the same 5KB). Weights are
//       wave-uniform -> load via s_load (uniform global reads of ws) and
//       feed v_pk_fma_f32 directly with its one legal SGPR operand.
//       LDS usage: ZERO. Weight VGPR footprint: ZERO.
// Per j per row-pair: 4 pk_fma (L1 chain) + 2 v_max + 4 pk_fma (L2, tied)
// = 10 VALU; + 1 s->v copy of b1 pair per j. ~2830 VALU instrs/thread.
// VALU floor ~19us, HBM floor ~16us.

#define BATCH   4194304
#define HID     64
#define ROWS    8                         // 4 packed pairs per thread
#define TPB     256
#define NBLK    (BATCH / (TPB * ROWS))    // 2048 blocks

// ws layout (floats): per j (20-float block, 80B, 16B-aligned):
//   [j*20 + 0.. 7]  w1 duplicated: {w1x,w1x,w1y,w1y,w1z,w1z,w1w,w1w}  (input-scale folded)
//   [j*20 + 8..15]  w2 duplicated: {w2x,w2x,w2y,w2y,w2z,w2z,w2w,w2w}
//   [j*20 +16..17]  {b1'j, b1'j}
//   [j*20 +18..19]  pad
//   [1280..1283]    b2[0..3]
#define WS_FLOATS 1284

typedef float v2f __attribute__((ext_vector_type(2)));
typedef float v4f __attribute__((ext_vector_type(4)));

// d = a*w + c. w is wave-uniform -> SGPR pair {w,w} (the single legal SGPR
// operand). c in VGPR (used for the b1-init fma; the s->v copy of b1 is
// hoisted once per j by CSE since all 4 pairs share it).
static __device__ __forceinline__ v2f pk_fma_new(v2f a, v2f w, v2f c) {
    v2f d;
    asm("v_pk_fma_f32 %0, %1, %2, %3" : "=v"(d) : "v"(a), "s"(w), "v"(c));
    return d;
}

// acc = a*w + acc, in place (tied "+v": no result-marshaling movs).
static __device__ __forceinline__ void pk_fma_acc(v2f& acc, v2f a, v2f w) {
    asm("v_pk_fma_f32 %0, %1, %2, %0" : "+v"(acc) : "v"(a), "s"(w));
}

// relu on a pair: 2x v_max_f32 (no packed f32 max on CDNA).
static __device__ __forceinline__ v2f vmax0(v2f t) {
    v2f r;
    r.x = fmaxf(t.x, 0.0f);
    r.y = fmaxf(t.y, 0.0f);
    return r;
}

__global__ __launch_bounds__(64)
void prep_kernel(const float* __restrict__ W1, const float* __restrict__ b1,
                 const float* __restrict__ W2, const float* __restrict__ b2,
                 float* __restrict__ ws) {
    const float A[4] = {0.001f, 0.02f, 0.05f, 0.001f};
    const float S[4] = {0.003f, 0.03f, 0.15f, 0.003f};  // span = B - A
    int j = threadIdx.x;  // 0..63
    if (j < HID) {
        float bb = b1[j];
        #pragma unroll
        for (int k = 0; k < 4; ++k) {
            float wv = W1[k * HID + j];
            float wd = wv / S[k];               // fold input scaling into W1
            bb -= (A[k] / S[k]) * wv;           // and into b1
            ws[j * 20 + 2 * k]     = wd;
            ws[j * 20 + 2 * k + 1] = wd;
        }
        #pragma unroll
        for (int i = 0; i < 4; ++i) {
            float wv = W2[j * 4 + i];
            ws[j * 20 + 8 + 2 * i]     = wv;
            ws[j * 20 + 8 + 2 * i + 1] = wv;
        }
        ws[j * 20 + 16] = bb;
        ws[j * 20 + 17] = bb;
        ws[j * 20 + 18] = 0.0f;
        ws[j * 20 + 19] = 0.0f;
    }
    if (j < 4) ws[1280 + j] = b2[j];
}

__global__ __launch_bounds__(TPB, 4)
void mlp_kernel(const float* __restrict__ x, const float* __restrict__ ws,
                float* __restrict__ out) {
    const long base = (long)blockIdx.x * (TPB * ROWS) + threadIdx.x;
    const v4f* __restrict__ x4   = (const v4f*)x;
    v4f* __restrict__       out4 = (v4f*)out;
    const v2f* __restrict__ wsp  = (const v2f*)ws;   // uniform reads -> s_load

    // 8 rows, coalesced dwordx4 loads.
    v4f xr[ROWS];
    #pragma unroll
    for (int r = 0; r < ROWS; ++r) xr[r] = x4[base + (long)r * TPB];

    // Pack rows (2p, 2p+1) element-wise into float2 pairs (one-time movs).
    v2f X[4][4];
    #pragma unroll
    for (int p = 0; p < 4; ++p)
        #pragma unroll
        for (int e = 0; e < 4; ++e) {
            v2f t = {xr[2 * p][e], xr[2 * p + 1][e]};
            X[p][e] = t;
        }

    // Acc: Ac[p][c] = {y_c(row 2p), y_c(row 2p+1)}, init b2[c] (uniform).
    v2f Ac[4][4];
    #pragma unroll
    for (int c = 0; c < 4; ++c) {
        float b2c = ws[1280 + c];
        #pragma unroll
        for (int p = 0; p < 4; ++p) {
            v2f t = {b2c, b2c};
            Ac[p][c] = t;
        }
    }

    // Per j: 16 contiguous uniform dwords (w1 dup, w2 dup) + b1 pair ->
    // s_load_dwordx16 + s_load_dwordx2. Zero LDS, zero weight VGPRs.
    #pragma unroll 4
    for (int j = 0; j < HID; ++j) {
        const v2f w10 = wsp[j * 10 + 0];   // {w1x,w1x}
        const v2f w11 = wsp[j * 10 + 1];   // {w1y,w1y}
        const v2f w12 = wsp[j * 10 + 2];   // {w1z,w1z}
        const v2f w13 = wsp[j * 10 + 3];   // {w1w,w1w}
        const v2f w20 = wsp[j * 10 + 4];   // {w2x,w2x}
        const v2f w21 = wsp[j * 10 + 5];   // {w2y,w2y}
        const v2f w22 = wsp[j * 10 + 6];   // {w2z,w2z}
        const v2f w23 = wsp[j * 10 + 7];   // {w2w,w2w}
        const v2f bb  = wsp[j * 10 + 8];   // {b1'ated,b1'}  (s->v copied once/j)
        #pragma unroll
        for (int p = 0; p < 4; ++p) {
            v2f t = pk_fma_new(X[p][0], w10, bb);
            pk_fma_acc(t, X[p][1], w11);
            pk_fma_acc(t, X[p][2], w12);
            pk_fma_acc(t, X[p][3], w13);
            t = vmax0(t);
            pk_fma_acc(Ac[p][0], t, w20);
            pk_fma_acc(Ac[p][1], t, w21);
            pk_fma_acc(Ac[p][2], t, w22);
            pk_fma_acc(Ac[p][3], t, w23);
        }
    }

    // z = A + span * sigmoid(y):  z_c = fma(span_c, 1/(1+exp(-y_c)), A_c)
    const float LA[4] = {0.001f, 0.02f, 0.05f, 0.001f};
    const float LS[4] = {0.003f, 0.03f, 0.15f, 0.003f};
    #pragma unroll
    for (int p = 0; p < 4; ++p) {
        v4f z0, z1;
        #pragma unroll
        for (int c = 0; c < 4; ++c) {
            z0[c] = fmaf(LS[c], 1.0f / (1.0f + __expf(-Ac[p][c].x)), LA[c]);
            z1[c] = fmaf(LS[c], 1.0f / (1.0f + __expf(-Ac[p][c].y)), LA[c]);
        }
        out4[base + (long)(2 * p) * TPB]     = z0;
        out4[base + (long)(2 * p + 1) * TPB] = z1;
    }
}

extern "C" void kernel_launch(void* const* d_in, const int* in_sizes, int n_in,
                              void* d_out, int out_size, void* d_ws, size_t ws_size,
                              hipStream_t stream) {
    const float* x  = (const float*)d_in[0];
    const float* W1 = (const float*)d_in[1];
    const float* b1 = (const float*)d_in[2];
    const float* W2 = (const float*)d_in[3];
    const float* b2 = (const float*)d_in[4];
    float* out = (float*)d_out;
    float* ws  = (float*)d_ws;

    prep_kernel<<<1, 64, 0, stream>>>(W1, b1, W2, b2, ws);
    mlp_kernel<<<NBLK, TPB, 0, stream>>>(x, ws, out);
}